// Round 1
// baseline (14392.537 us; speedup 1.0000x reference)
//
#include <hip/hip_runtime.h>
#include <math.h>

#define NT 1024

__device__ __forceinline__ float sigf(float x)   { return 1.0f / (1.0f + __expf(-x)); }
__device__ __forceinline__ float tanhf_(float x) { return 1.0f - 2.0f / (1.0f + __expf(2.0f * x)); }

__device__ __forceinline__ float dot4(float4 a, float4 b) {
    return a.x * b.x + a.y * b.y + a.z * b.z + a.w * b.w;
}
__device__ __forceinline__ float red16(float v) {
    v += __shfl_xor(v, 1); v += __shfl_xor(v, 2);
    v += __shfl_xor(v, 4); v += __shfl_xor(v, 8);
    return v;
}

// One block per batch element. 1024 threads. All recurrent state in LDS.
extern "C" __global__ void __launch_bounds__(NT)
attn_lstm(const float* __restrict__ inp,
          const float* __restrict__ wihe0, const float* __restrict__ wihe1,
          const float* __restrict__ whhe,  const float* __restrict__ bihe,
          const float* __restrict__ bhhe,
          const float* __restrict__ wihd0, const float* __restrict__ wihd0r,
          const float* __restrict__ wihd1,
          const float* __restrict__ whhd,  const float* __restrict__ bihd,
          const float* __restrict__ bhhd,
          const float* __restrict__ aw1,   const float* __restrict__ ab1,
          const float* __restrict__ aw2,
          const float* __restrict__ dw1,   const float* __restrict__ db1,
          const float* __restrict__ dw2,
          const float* __restrict__ pw,    const float* __restrict__ pb,
          float* __restrict__ out, int use_repack)
{
    extern __shared__ __align__(16) float sm[];
    float* h0     = sm;             // 256   layer0 h
    float* c0     = h0 + 256;       // 256   layer0 c
    float* hc1    = c0 + 256;       // 512   layer1 [h | c]
    float* full   = hc1 + 512;      // 260   enc: x_t*a in [0,64); dec: [partial|d_t|0,0,0]
    float* gates  = full + 260;     // 1024
    float* scoreS = gates + 1024;   // 64
    float* aS     = scoreS + 64;    // 64
    float* hctS   = aS + 64;        // 256
    float* decin  = hctS + 256;     // 64
    float* hexp   = decin + 64;     // 64*256 = 16384 (h_expanded)
    float* xeT    = hexp + 16384;   // 64*68 (x_enc transposed, padded stride 68)

    const int b   = blockIdx.x;
    const int tid = threadIdx.x;

    // ---- init: zero h/c state + full buffer; stage inputs ----
    for (int i = tid; i < 1284; i += NT) sm[i] = 0.0f;
    const float* ib = inp + b * (64 * 65);
    for (int i = tid; i < 4096; i += NT) {
        int t = i & 63, e = i >> 6;
        xeT[e * 68 + t] = ib[t * 65 + 1 + e];   // x_encT[e][t]
    }
    if (tid < 64) decin[tid] = ib[tid * 65];
    __syncthreads();

    const int g16 = tid >> 4;   // 0..63  (row index e / t for attention phases)
    const int q16 = tid & 15;

    // ---- P precompute (encoder attention: input_permuted part + bias) -> regs ----
    float Preg[4], w2r[4];
    #pragma unroll
    for (int jj = 0; jj < 4; ++jj) {
        int j = q16 + 16 * jj;
        w2r[jj] = aw2[j];
        float acc = ab1[j];
        const float4* w4 = (const float4*)(aw1 + j * 576 + 512);
        const float4* x4 = (const float4*)(xeT + g16 * 68);
        #pragma unroll 4
        for (int k = 0; k < 16; ++k) acc += dot4(w4[k], x4[k]);
        Preg[jj] = acc;
    }

    // ================= encoder: 64 steps =================
    for (int t = 0; t < 64; ++t) {
        // E1: hct[j] = [h1;c1] . aw1[j, 0:512)   (j < 64)
        {
            const float* w = aw1 + g16 * 576;
            float acc = 0.f;
            #pragma unroll 8
            for (int i = 0; i < 32; ++i) {
                int k = q16 + 16 * i;
                acc += hc1[k] * w[k];
            }
            acc = red16(acc);
            if (q16 == 0) hctS[g16] = acc;
        }
        __syncthreads();
        // E2: score[e] = sum_j tanh(P[e][j] + hct[j]) * w2[j]
        {
            float s = 0.f;
            #pragma unroll
            for (int jj = 0; jj < 4; ++jj) {
                int j = q16 + 16 * jj;
                s += tanhf_(Preg[jj] + hctS[j]) * w2r[jj];
            }
            s = red16(s);
            if (q16 == 0) scoreS[g16] = s;
        }
        __syncthreads();
        // E3: softmax over e (wave 0) ; x_in = x_t * a
        if (tid < 64) {
            float v = scoreS[tid];
            float m = v;
            #pragma unroll
            for (int d = 1; d < 64; d <<= 1) m = fmaxf(m, __shfl_xor(m, d));
            float ex = __expf(v - m);
            float s = ex;
            #pragma unroll
            for (int d = 1; d < 64; d <<= 1) s += __shfl_xor(s, d);
            full[tid] = (ex / s) * xeT[tid * 68 + t];
        }
        __syncthreads();
        // E4: layer0 gates (row per thread)
        {
            int j = tid;
            float acc = bihe[j] + bhhe[j];
            const float4* wi = (const float4*)(wihe0 + (j << 6));
            const float4* xf = (const float4*)full;
            #pragma unroll 4
            for (int k = 0; k < 16; ++k) acc += dot4(wi[k], xf[k]);
            const float4* wh = (const float4*)(whhe + (j << 8));
            const float4* h4 = (const float4*)h0;
            #pragma unroll 4
            for (int k = 0; k < 64; ++k) acc += dot4(wh[k], h4[k]);
            gates[j] = acc;
        }
        __syncthreads();
        // E5: elementwise layer0
        if (tid < 256) {
            int j = tid;
            float cn = sigf(gates[256 + j]) * c0[j] + sigf(gates[j]) * tanhf_(gates[512 + j]);
            float hn = sigf(gates[768 + j]) * tanhf_(cn);
            c0[j] = cn; h0[j] = hn;
        }
        __syncthreads();
        // E6: layer1 gates
        {
            int j = tid;
            float acc = bihe[1024 + j] + bhhe[1024 + j];
            const float4* wi = (const float4*)(wihe1 + (j << 8));
            const float4* h4 = (const float4*)h0;
            #pragma unroll 4
            for (int k = 0; k < 64; ++k) acc += dot4(wi[k], h4[k]);
            const float4* wh = (const float4*)(whhe + 262144 + (j << 8));
            const float4* h14 = (const float4*)hc1;
            #pragma unroll 4
            for (int k = 0; k < 64; ++k) acc += dot4(wh[k], h14[k]);
            gates[j] = acc;
        }
        __syncthreads();
        // E7: elementwise layer1 + record h_expanded
        if (tid < 256) {
            int j = tid;
            float cn = sigf(gates[256 + j]) * hc1[256 + j] + sigf(gates[j]) * tanhf_(gates[512 + j]);
            float hn = sigf(gates[768 + j]) * tanhf_(cn);
            hc1[256 + j] = cn; hc1[j] = hn;
            hexp[t * 256 + j] = hn;
        }
        __syncthreads();
    }

    // ---- re-zero recurrent state; Pd precompute (decoder attention const part) -> regs ----
    sm[tid] = 0.0f;  // h0, c0, hc1 are the first 1024 floats
    float Pdreg[16], w2dr[16];
    #pragma unroll
    for (int jj = 0; jj < 16; ++jj) {
        int j = q16 + 16 * jj;
        w2dr[jj] = dw2[j];
        float acc = db1[j];
        const float4* w4 = (const float4*)(dw1 + j * 768 + 512);
        const float4* x4 = (const float4*)(hexp + g16 * 256);
        #pragma unroll 4
        for (int k = 0; k < 64; ++k) acc += dot4(w4[k], x4[k]);
        Pdreg[jj] = acc;
    }
    __syncthreads();

    // ================= decoder: 64 steps =================
    const int j4 = tid >> 2;   // 0..255
    const int q4 = tid & 3;
    for (int t = 0; t < 64; ++t) {
        // D1: hctd[j] = [h1;c1] . dw1[j, 0:512)   (j < 256)
        {
            const float4* w4 = (const float4*)(dw1 + j4 * 768 + q4 * 128);
            const float4* x4 = (const float4*)(hc1 + q4 * 128);
            float acc = 0.f;
            #pragma unroll 4
            for (int i = 0; i < 32; ++i) acc += dot4(w4[i], x4[i]);
            acc += __shfl_xor(acc, 1);
            acc += __shfl_xor(acc, 2);
            if (q4 == 0) hctS[j4] = acc;
        }
        __syncthreads();
        // D2: score[t'] = sum_j tanh(Pd[t'][j] + hctd[j]) * w2d[j]
        {
            float s = 0.f;
            #pragma unroll
            for (int jj = 0; jj < 16; ++jj) {
                int j = q16 + 16 * jj;
                s += tanhf_(Pdreg[jj] + hctS[j]) * w2dr[jj];
            }
            s = red16(s);
            if (q16 == 0) scoreS[g16] = s;
        }
        __syncthreads();
        // D3: softmax over t' (wave 0) -> aS ; stage d_t
        if (tid < 64) {
            float v = scoreS[tid];
            float m = v;
            #pragma unroll
            for (int d = 1; d < 64; d <<= 1) m = fmaxf(m, __shfl_xor(m, d));
            float ex = __expf(v - m);
            float s = ex;
            #pragma unroll
            for (int d = 1; d < 64; d <<= 1) s += __shfl_xor(s, d);
            aS[tid] = ex / s;
            if (tid == 0) full[256] = decin[t];
        }
        __syncthreads();
        // D4: partial[h] = sum_t hexp[t][h] * a[t]  -> full[0,256)
        {
            float acc = 0.f;
            #pragma unroll 4
            for (int i = 0; i < 16; ++i) {
                int tt = q4 + 4 * i;
                acc += hexp[tt * 256 + j4] * aS[tt];
            }
            acc += __shfl_xor(acc, 1);
            acc += __shfl_xor(acc, 2);
            if (q4 == 0) full[j4] = acc;
        }
        __syncthreads();
        // D5: layer0 gates (input width 257, padded to 260 if repacked)
        {
            int j = tid;
            float acc = bihd[j] + bhhd[j];
            if (use_repack) {
                const float4* wi = (const float4*)(wihd0r + j * 260);
                const float4* xf = (const float4*)full;
                #pragma unroll 5
                for (int k = 0; k < 65; ++k) acc += dot4(wi[k], xf[k]);
            } else {
                const float* wi = wihd0 + j * 257;
                #pragma unroll 8
                for (int k = 0; k < 257; ++k) acc += wi[k] * full[k];
            }
            const float4* wh = (const float4*)(whhd + (j << 8));
            const float4* h4 = (const float4*)h0;
            #pragma unroll 4
            for (int k = 0; k < 64; ++k) acc += dot4(wh[k], h4[k]);
            gates[j] = acc;
        }
        __syncthreads();
        // D6: elementwise layer0
        if (tid < 256) {
            int j = tid;
            float cn = sigf(gates[256 + j]) * c0[j] + sigf(gates[j]) * tanhf_(gates[512 + j]);
            float hn = sigf(gates[768 + j]) * tanhf_(cn);
            c0[j] = cn; h0[j] = hn;
        }
        __syncthreads();
        // D7: layer1 gates
        {
            int j = tid;
            float acc = bihd[1024 + j] + bhhd[1024 + j];
            const float4* wi = (const float4*)(wihd1 + (j << 8));
            const float4* h4 = (const float4*)h0;
            #pragma unroll 4
            for (int k = 0; k < 64; ++k) acc += dot4(wi[k], h4[k]);
            const float4* wh = (const float4*)(whhd + 262144 + (j << 8));
            const float4* h14 = (const float4*)hc1;
            #pragma unroll 4
            for (int k = 0; k < 64; ++k) acc += dot4(wh[k], h14[k]);
            gates[j] = acc;
        }
        __syncthreads();
        // D8: elementwise layer1
        if (tid < 256) {
            int j = tid;
            float cn = sigf(gates[256 + j]) * hc1[256 + j] + sigf(gates[j]) * tanhf_(gates[512 + j]);
            float hn = sigf(gates[768 + j]) * tanhf_(cn);
            hc1[256 + j] = cn; hc1[j] = hn;
        }
        __syncthreads();
    }

    // ---- output: |[h1 ; partial] . proj_w + proj_b| ----
    if (tid < 64) {
        float acc = 0.f;
        #pragma unroll
        for (int i = 0; i < 8; ++i) {
            int k = tid + 64 * i;
            float v = (k < 256) ? hc1[k] : full[k - 256];
            acc += v * pw[k];
        }
        #pragma unroll
        for (int d = 1; d < 64; d <<= 1) acc += __shfl_xor(acc, d);
        if (tid == 0) out[b] = fabsf(acc + pb[0]);
    }
}

// Repack w_ih_d0 [1024][257] -> [1024][260] (16B-aligned rows, zero pad).
extern "C" __global__ void repack_k(const float* __restrict__ src, float* __restrict__ dst) {
    int idx = blockIdx.x * blockDim.x + threadIdx.x;
    if (idx >= 1024 * 260) return;
    int j = idx / 260;
    int k = idx - j * 260;
    dst[idx] = (k < 257) ? src[j * 257 + k] : 0.0f;
}

extern "C" void kernel_launch(void* const* d_in, const int* in_sizes, int n_in,
                              void* d_out, int out_size, void* d_ws, size_t ws_size,
                              hipStream_t stream) {
    const float* inp   = (const float*)d_in[0];
    const float* wihe0 = (const float*)d_in[1];
    const float* wihe1 = (const float*)d_in[2];
    const float* whhe  = (const float*)d_in[3];
    const float* bihe  = (const float*)d_in[4];
    const float* bhhe  = (const float*)d_in[5];
    const float* wihd0 = (const float*)d_in[6];
    const float* wihd1 = (const float*)d_in[7];
    const float* whhd  = (const float*)d_in[8];
    const float* bihd  = (const float*)d_in[9];
    const float* bhhd  = (const float*)d_in[10];
    const float* aw1   = (const float*)d_in[11];
    const float* ab1   = (const float*)d_in[12];
    const float* aw2   = (const float*)d_in[13];
    const float* dw1   = (const float*)d_in[14];
    const float* db1   = (const float*)d_in[15];
    const float* dw2   = (const float*)d_in[16];
    const float* pw    = (const float*)d_in[17];
    const float* pb    = (const float*)d_in[18];
    float* out = (float*)d_out;

    const size_t repack_bytes = (size_t)1024 * 260 * sizeof(float);
    const int use_repack = (ws_size >= repack_bytes) ? 1 : 0;
    float* wr = (float*)d_ws;
    if (use_repack)
        repack_k<<<(1024 * 260 + 255) / 256, 256, 0, stream>>>(wihd0, wr);

    const int smem_bytes = 23492 * sizeof(float);  // ~94 KB
    hipFuncSetAttribute((const void*)attn_lstm,
                        hipFuncAttributeMaxDynamicSharedMemorySize, smem_bytes);
    attn_lstm<<<64, NT, smem_bytes, stream>>>(
        inp, wihe0, wihe1, whhe, bihe, bhhe,
        wihd0, use_repack ? wr : wihd0, wihd1, whhd, bihd, bhhd,
        aw1, ab1, aw2, dw1, db1, dw2, pw, pb, out, use_repack);
}